// Round 2
// baseline (9888.341 us; speedup 1.0000x reference)
//
#include <hip/hip_runtime.h>
#include <hip/hip_bf16.h>
#include <math.h>

// Problem constants
constexpr int S    = 2048;
constexpr int D    = 1024;
constexpr int NH   = 16;
constexpr int HD   = 64;
constexpr int RD   = 32;
constexpr int KVC  = 256;
constexpr int QC   = 384;
constexpr int H2   = 32;      // 2*NH half-heads
constexpr int QKD  = 48;      // HD/2 + RD/2
constexpr float SCALE    = 0.14433756729740643f;  // 48^-0.5
constexpr float LAM_INIT = 0.2f;                  // 0.8 - 0.6*exp(0)
constexpr float EPS      = 1e-5f;

// ---------------------------------------------------------------- GEMM (f32)
// C[M,N] = A[M,K] @ B[K,N]. 128x128 tile, BK=16, 256 threads, 8x8 per thread.
// Requires M%128==0, K%16==0, N%4==0 (true for all call sites). N-edge guarded.
__global__ __launch_bounds__(256) void gemm_f32(
    const float* __restrict__ A, const float* __restrict__ B,
    float* __restrict__ C, int M, int K, int N) {
  __shared__ float As[16][128];
  __shared__ float Bs[16][128];
  const int tid = threadIdx.x;
  const int m0 = blockIdx.y * 128, n0 = blockIdx.x * 128;
  const int ty = tid >> 4, tx = tid & 15;
  float acc[8][8] = {};
  for (int k0 = 0; k0 < K; k0 += 16) {
#pragma unroll
    for (int it = 0; it < 2; ++it) {
      const int am = (tid >> 2) + it * 64;
      const int ak = (tid & 3) * 4;
      float4 a4 = *(const float4*)&A[(size_t)(m0 + am) * K + k0 + ak];
      As[ak + 0][am] = a4.x; As[ak + 1][am] = a4.y;
      As[ak + 2][am] = a4.z; As[ak + 3][am] = a4.w;
    }
#pragma unroll
    for (int it = 0; it < 2; ++it) {
      const int bk = (tid >> 5) + it * 8;
      const int bn = (tid & 31) * 4;
      const int gn = n0 + bn;
      float4 b4 = make_float4(0.f, 0.f, 0.f, 0.f);
      if (gn < N) b4 = *(const float4*)&B[(size_t)(k0 + bk) * N + gn];
      *(float4*)&Bs[bk][bn] = b4;
    }
    __syncthreads();
#pragma unroll
    for (int kk = 0; kk < 16; ++kk) {
      float a[8], b[8];
      *(float4*)&a[0] = *(const float4*)&As[kk][ty * 8];
      *(float4*)&a[4] = *(const float4*)&As[kk][ty * 8 + 4];
      *(float4*)&b[0] = *(const float4*)&Bs[kk][tx * 8];
      *(float4*)&b[4] = *(const float4*)&Bs[kk][tx * 8 + 4];
#pragma unroll
      for (int r = 0; r < 8; ++r)
#pragma unroll
        for (int c = 0; c < 8; ++c) acc[r][c] += a[r] * b[c];
    }
    __syncthreads();
  }
#pragma unroll
  for (int r = 0; r < 8; ++r) {
    const int gm = m0 + ty * 8 + r;
#pragma unroll
    for (int c4 = 0; c4 < 2; ++c4) {
      const int gn = n0 + tx * 8 + c4 * 4;
      if (gn < N) {
        float4 v = make_float4(acc[r][c4 * 4], acc[r][c4 * 4 + 1],
                               acc[r][c4 * 4 + 2], acc[r][c4 * 4 + 3]);
        *(float4*)&C[(size_t)gm * N + gn] = v;
      }
    }
  }
}

// ------------------------------------------------------------ row rmsnorm
__global__ __launch_bounds__(256) void rmsnorm_rows(
    const float* __restrict__ in, const float* __restrict__ w,
    float* __restrict__ out, int stride_in, int width) {
  const int row = blockIdx.x;
  const float* x = in + (size_t)row * stride_in;
  float ss = 0.f;
  for (int j = threadIdx.x; j < width; j += 256) { float v = x[j]; ss += v * v; }
  __shared__ float red[256];
  red[threadIdx.x] = ss;
  __syncthreads();
  for (int o = 128; o; o >>= 1) {
    if (threadIdx.x < o) red[threadIdx.x] += red[threadIdx.x + o];
    __syncthreads();
  }
  const float sc = rsqrtf(red[0] / (float)width + EPS);
  for (int j = threadIdx.x; j < width; j += 256)
    out[(size_t)row * width + j] = x[j] * sc * w[j];
}

// ------------------------------------------- assemble q_f^T, k_f^T with RoPE
// qfT/kfT layout: [h2][48][S]
__global__ __launch_bounds__(64) void assemble_qk(
    const float* __restrict__ qp, const float* __restrict__ kv,
    const float* __restrict__ c, const float* __restrict__ freqs,
    float* __restrict__ qfT, float* __restrict__ kfT) {
  const int h2 = blockIdx.x;
  const int s = blockIdx.y * 64 + threadIdx.x;
  const int m = h2 >> 1, e = h2 & 1;
  const int sp = s >> 2;  // s = sp*NSEQ + ns, NSEQ=4
  float cs[8], sn[8];
  if (sp > 0) {
#pragma unroll
    for (int t = 0; t < 8; ++t) {
      float a = freqs[(sp - 1) * 8 + t];
      cs[t] = cosf(a); sn[t] = sinf(a);
    }
  }
  // ---- q
  const float* qrow = qp + (size_t)s * (NH * (HD + RD)) + m * (HD + RD);
#pragma unroll
  for (int j = 0; j < 32; ++j)
    qfT[((size_t)(h2 * QKD + j)) * S + s] = qrow[e * 32 + j];
  float r[16];
#pragma unroll
  for (int j = 0; j < 16; ++j) r[j] = qrow[HD + e * 16 + j];
  if (sp > 0) {
#pragma unroll
    for (int t = 0; t < 8; ++t) {
      float a = r[2 * t], b = r[2 * t + 1];
      r[2 * t]     = a * cs[t] - b * sn[t];
      r[2 * t + 1] = a * sn[t] + b * cs[t];
    }
  }
#pragma unroll
  for (int j = 0; j < 16; ++j)
    qfT[((size_t)(h2 * QKD + 32 + j)) * S + s] = r[j];
  // ---- k
  const float* krow = kv + (size_t)s * (NH * 2 * HD) + m * (2 * HD);
#pragma unroll
  for (int j = 0; j < 32; ++j)
    kfT[((size_t)(h2 * QKD + j)) * S + s] = krow[e * 32 + j];
#pragma unroll
  for (int j = 0; j < 16; ++j)
    r[j] = c[(size_t)s * (KVC + RD) + KVC + e * 16 + j];
  if (sp > 0) {
#pragma unroll
    for (int t = 0; t < 8; ++t) {
      float a = r[2 * t], b = r[2 * t + 1];
      r[2 * t]     = a * cs[t] - b * sn[t];
      r[2 * t + 1] = a * sn[t] + b * cs[t];
    }
  }
#pragma unroll
  for (int j = 0; j < 16; ++j)
    kfT[((size_t)(h2 * QKD + 32 + j)) * S + s] = r[j];
}

// v layout [h][S][64]
__global__ __launch_bounds__(256) void assemble_v(
    const float* __restrict__ kv, float* __restrict__ vv) {
  const int i = blockIdx.x * 256 + threadIdx.x;  // < 16*2048*64
  const int dd = i & 63;
  const int s = (i >> 6) & (S - 1);
  const int h = i >> 17;
  vv[i] = kv[(size_t)s * (NH * 2 * HD) + h * (2 * HD) + HD + dd];
}

// lam scalar
__global__ __launch_bounds__(64) void compute_lam(
    const float* __restrict__ lk1, const float* __restrict__ lk2,
    const float* __restrict__ lq1, const float* __restrict__ lq2,
    float* __restrict__ lam) {
  const int t = threadIdx.x;
  float p1 = (t < 32) ? lk1[t] * lq1[t] : 0.f;
  float p2 = (t < 32) ? lk2[t] * lq2[t] : 0.f;
  for (int o = 16; o; o >>= 1) {
    p1 += __shfl_down(p1, o);
    p2 += __shfl_down(p2, o);
  }
  if (t == 0) *lam = expf(p1) - expf(p2) + LAM_INIT;
}

// 64x64x48 score tile: s[r][c] += sum_j Q[j][ty*4+r] * Kt[j][tx*4+c]
__device__ __forceinline__ void score_gemm(
    const float (*__restrict__ Q)[64], const float (*__restrict__ Kt)[64],
    int ty, int tx, float s[4][4]) {
#pragma unroll
  for (int j = 0; j < QKD; ++j) {
    float4 a4 = *(const float4*)&Q[j][ty * 4];
    float4 b4 = *(const float4*)&Kt[j][tx * 4];
    const float a[4] = {a4.x, a4.y, a4.z, a4.w};
    const float b[4] = {b4.x, b4.y, b4.z, b4.w};
#pragma unroll
    for (int r = 0; r < 4; ++r)
#pragma unroll
      for (int c = 0; c < 4; ++c) s[r][c] += a[r] * b[c];
  }
}

// ------------------------------------------ Pass A: per-row max + 1/denom
// grid (16 pairs, 32 h2); block handles q-tiles pair and 31-pair (33 k-tiles).
__global__ __launch_bounds__(256) void attn_md(
    const float* __restrict__ qfT, const float* __restrict__ kfT,
    float* __restrict__ mOut, float* __restrict__ rdOut) {
  const int pair = blockIdx.x, h2 = blockIdx.y;
  __shared__ float Qs[QKD][64], Ks[QKD][64];
  __shared__ float sm[64][17], sd[64][17];
  const int tid = threadIdx.x, ty = tid >> 4, tx = tid & 15;
#pragma unroll
  for (int half = 0; half < 2; ++half) {
    const int q0 = (half ? (31 - pair) : pair) * 64;
    for (int idx = tid; idx < QKD * 64; idx += 256) {
      const int j = idx >> 6, qi = idx & 63;
      Qs[j][qi] = qfT[((size_t)(h2 * QKD + j)) * S + q0 + qi];
    }
    float ml[4] = {-1e30f, -1e30f, -1e30f, -1e30f};
    float dl[4] = {0.f, 0.f, 0.f, 0.f};
    __syncthreads();
    for (int k0 = 0; k0 <= q0; k0 += 64) {
      for (int idx = tid; idx < QKD * 64; idx += 256) {
        const int j = idx >> 6, ki = idx & 63;
        Ks[j][ki] = kfT[((size_t)(h2 * QKD + j)) * S + k0 + ki];
      }
      __syncthreads();
      float s[4][4] = {};
      score_gemm(Qs, Ks, ty, tx, s);
      const bool diag = (k0 == q0);
#pragma unroll
      for (int r = 0; r < 4; ++r) {
        float av[4];
        float tm = ml[r];
#pragma unroll
        for (int c = 0; c < 4; ++c) {
          av[c] = fabsf(s[r][c] * SCALE);
          const bool valid = !diag || (tx * 4 + c <= ty * 4 + r);
          if (valid) tm = fmaxf(tm, av[c]);
        }
        float add = 0.f;
#pragma unroll
        for (int c = 0; c < 4; ++c) {
          const bool valid = !diag || (tx * 4 + c <= ty * 4 + r);
          if (valid) add += expf(av[c] - tm);
        }
        dl[r] = dl[r] * expf(ml[r] - tm) + add;
        ml[r] = tm;
      }
      __syncthreads();
    }
#pragma unroll
    for (int r = 0; r < 4; ++r) { sm[ty * 4 + r][tx] = ml[r]; sd[ty * 4 + r][tx] = dl[r]; }
    __syncthreads();
    if (tid < 64) {
      float M = -1e30f;
#pragma unroll
      for (int t = 0; t < 16; ++t) M = fmaxf(M, sm[tid][t]);
      float Dd = 0.f;
#pragma unroll
      for (int t = 0; t < 16; ++t) Dd += sd[tid][t] * expf(sm[tid][t] - M);
      mOut[h2 * S + q0 + tid] = M;
      rdOut[h2 * S + q0 + tid] = 1.0f / Dd;
    }
    __syncthreads();
  }
}

// ------------------------------------------ Pass B: g[h][k] = mean_q p1[q,k]
// grid (16 pairs, 16 h); block handles k-tiles pair and 31-pair.
__global__ __launch_bounds__(256) void attn_g(
    const float* __restrict__ qfT, const float* __restrict__ kfT,
    const float* __restrict__ mIn, const float* __restrict__ rdIn,
    float* __restrict__ g) {
  const int pair = blockIdx.x, h = blockIdx.y, h2 = 2 * h;
  __shared__ float Ks[QKD][64], Qs[QKD][64];
  __shared__ float mq[64], rq[64];
  __shared__ float red[64][17];
  const int tid = threadIdx.x, ty = tid >> 4, tx = tid & 15;
#pragma unroll
  for (int half = 0; half < 2; ++half) {
    const int k0 = (half ? (31 - pair) : pair) * 64;
    for (int idx = tid; idx < QKD * 64; idx += 256) {
      const int j = idx >> 6, ki = idx & 63;
      Ks[j][ki] = kfT[((size_t)(h2 * QKD + j)) * S + k0 + ki];
    }
    float acc[4] = {0.f, 0.f, 0.f, 0.f};
    __syncthreads();
    for (int q0 = k0; q0 < S; q0 += 64) {
      for (int idx = tid; idx < QKD * 64; idx += 256) {
        const int j = idx >> 6, qi = idx & 63;
        Qs[j][qi] = qfT[((size_t)(h2 * QKD + j)) * S + q0 + qi];
      }
      if (tid < 64) {
        mq[tid] = mIn[h2 * S + q0 + tid];
        rq[tid] = rdIn[h2 * S + q0 + tid];
      }
      __syncthreads();
      float s[4][4] = {};
      score_gemm(Qs, Ks, ty, tx, s);
      const bool diag = (q0 == k0);
#pragma unroll
      for (int r = 0; r < 4; ++r) {
        const float mv = mq[ty * 4 + r], rv = rq[ty * 4 + r];
#pragma unroll
        for (int c = 0; c < 4; ++c) {
          const bool valid = !diag || (ty * 4 + r >= tx * 4 + c);
          if (valid) {
            const float sv = s[r][c] * SCALE;
            const float av = fabsf(sv);
            const float sg = (sv > 0.f) ? 1.f : ((sv < 0.f) ? -1.f : 0.f);
            acc[c] += sg * expf(av - mv) * rv;
          }
        }
      }
      __syncthreads();
    }
#pragma unroll
    for (int c = 0; c < 4; ++c) red[tx * 4 + c][ty] = acc[c];
    __syncthreads();
    if (tid < 64) {
      float sum = 0.f;
#pragma unroll
      for (int t = 0; t < 16; ++t) sum += red[tid][t];
      g[h * S + k0 + tid] = sum * (1.0f / (float)S);
    }
    __syncthreads();
  }
}

// --------------------------- Pass C: prefix sum over k of g[h,k]*v[h,k,dd]
__global__ __launch_bounds__(64) void attn_gvc(
    const float* __restrict__ g, const float* __restrict__ vv,
    float* __restrict__ gvc) {
  const int h = blockIdx.x, dd = threadIdx.x;
  float run = 0.f;
#pragma unroll 4
  for (int k = 0; k < S; ++k) {
    run += g[h * S + k] * vv[((size_t)(h * S + k)) * 64 + dd];
    gvc[((size_t)(h * S + k)) * 64 + dd] = run;
  }
}

// --------------- Pass D: out = (p1 - lam*p2)@V + lam*gvc ; fused rmsnorm
// grid (16 pairs, 16 h); block handles q-tiles pair and 31-pair.
__global__ __launch_bounds__(256) void attn_out(
    const float* __restrict__ qfT, const float* __restrict__ kfT,
    const float* __restrict__ vv, const float* __restrict__ mIn,
    const float* __restrict__ rdIn, const float* __restrict__ gvc,
    const float* __restrict__ lamPtr, const float* __restrict__ normW,
    float* __restrict__ normed) {
  const int pair = blockIdx.x, h = blockIdx.y;
  const int h2a = 2 * h, h2b = 2 * h + 1;
  __shared__ float Q1[QKD][64], Q2[QKD][64];
  __shared__ float Ps[64][68];            // padded: 16B-aligned rows, low-conflict
  __shared__ float KV[64 * 64];           // K tile [48][64], then V tile [64][64]
  __shared__ float m1s[64], r1s[64], m2s[64], r2s[64];
  __shared__ float rn[64][17];
  __shared__ float rs[64];
  const int tid = threadIdx.x, ty = tid >> 4, tx = tid & 15;
  const float lam = *lamPtr;
#pragma unroll
  for (int half = 0; half < 2; ++half) {
    const int q0 = (half ? (31 - pair) : pair) * 64;
    for (int idx = tid; idx < QKD * 64; idx += 256) {
      const int j = idx >> 6, qi = idx & 63;
      Q1[j][qi] = qfT[((size_t)(h2a * QKD + j)) * S + q0 + qi];
      Q2[j][qi] = qfT[((size_t)(h2b * QKD + j)) * S + q0 + qi];
    }
    if (tid < 64) {
      m1s[tid] = mIn[h2a * S + q0 + tid];
      r1s[tid] = rdIn[h2a * S + q0 + tid];
      m2s[tid] = mIn[h2b * S + q0 + tid];
      r2s[tid] = rdIn[h2b * S + q0 + tid];
    }
    float out[4][4] = {};
    __syncthreads();
    for (int k0 = 0; k0 <= q0; k0 += 64) {
      // K1 -> s1
      for (int idx = tid; idx < QKD * 64; idx += 256) {
        const int j = idx >> 6, ki = idx & 63;
        KV[j * 64 + ki] = kfT[((size_t)(h2a * QKD + j)) * S + k0 + ki];
      }
      __syncthreads();
      float s1[4][4] = {};
      score_gemm(Q1, (const float(*)[64])KV, ty, tx, s1);
      __syncthreads();
      // K2 -> s2
      for (int idx = tid; idx < QKD * 64; idx += 256) {
        const int j = idx >> 6, ki = idx & 63;
        KV[j * 64 + ki] = kfT[((size_t)(h2b * QKD + j)) * S + k0 + ki];
      }
      __syncthreads();
      float s2[4][4] = {};
      score_gemm(Q2, (const float(*)[64])KV, ty, tx, s2);
      // p tile
      const bool diag = (k0 == q0);
#pragma unroll
      for (int r = 0; r < 4; ++r) {
        const int row = ty * 4 + r;
        const float m1 = m1s[row], rd1 = r1s[row];
        const float m2 = m2s[row], rd2 = r2s[row];
#pragma unroll
        for (int c = 0; c < 4; ++c) {
          float p = 0.f;
          const bool valid = !diag || (tx * 4 + c <= row);
          if (valid) {
            const float v1 = s1[r][c] * SCALE, v2 = s2[r][c] * SCALE;
            const float sg1 = (v1 > 0.f) ? 1.f : ((v1 < 0.f) ? -1.f : 0.f);
            const float sg2 = (v2 > 0.f) ? 1.f : ((v2 < 0.f) ? -1.f : 0.f);
            p = sg1 * expf(fabsf(v1) - m1) * rd1
              - lam * (sg2 * expf(fabsf(v2) - m2) * rd2);
          }
          Ps[row][tx * 4 + c] = p;
        }
      }
      __syncthreads();  // Ps ready; KV free
      // V tile
      for (int idx = tid; idx < 64 * 64; idx += 256) {
        const int ki = idx >> 6, dd = idx & 63;
        KV[ki * 64 + dd] = vv[((size_t)(h * S + k0 + ki)) * 64 + dd];
      }
      __syncthreads();
      // PV: out[r][c] += sum_ki Ps[row][ki] * V[ki][col]
#pragma unroll
      for (int kq = 0; kq < 16; ++kq) {
        float pa[4][4];
#pragma unroll
        for (int r = 0; r < 4; ++r)
          *(float4*)pa[r] = *(const float4*)&Ps[ty * 4 + r][kq * 4];
#pragma unroll
        for (int u = 0; u < 4; ++u) {
          float4 b4 = *(const float4*)&KV[(kq * 4 + u) * 64 + tx * 4];
          const float b[4] = {b4.x, b4.y, b4.z, b4.w};
#pragma unroll
          for (int r = 0; r < 4; ++r)
#pragma unroll
            for (int c = 0; c < 4; ++c) out[r][c] += pa[r][u] * b[c];
        }
      }
      __syncthreads();
    }
    // epilogue: + lam*gvc, fused rmsnorm, store
#pragma unroll
    for (int r = 0; r < 4; ++r) {
      const int row = ty * 4 + r;
      float ss = 0.f;
#pragma unroll
      for (int c = 0; c < 4; ++c) {
        const float val = out[r][c]
            + lam * gvc[((size_t)(h * S + q0 + row)) * 64 + tx * 4 + c];
        out[r][c] = val;
        ss += val * val;
      }
      rn[row][tx] = ss;
    }
    __syncthreads();
    if (tid < 64) {
      float tot = 0.f;
#pragma unroll
      for (int t = 0; t < 16; ++t) tot += rn[tid][t];
      rs[tid] = rsqrtf(tot * (1.0f / 64.0f) + EPS);
    }
    __syncthreads();
#pragma unroll
    for (int r = 0; r < 4; ++r) {
      const int row = ty * 4 + r;
      const float sc = rs[row];
#pragma unroll
      for (int c = 0; c < 4; ++c) {
        const int dd = tx * 4 + c;
        normed[(size_t)(q0 + row) * D + h * 64 + dd] = out[r][c] * sc * normW[dd];
      }
    }
    __syncthreads();
  }
}

// ----------------------------------------------------------------- launch
extern "C" void kernel_launch(void* const* d_in, const int* in_sizes, int n_in,
                              void* d_out, int out_size, void* d_ws, size_t ws_size,
                              hipStream_t stream) {
  const float* x     = (const float*)d_in[0];
  // d_in[1] = mask (causal triu, recomputed implicitly)
  const float* freqs = (const float*)d_in[2];
  const float* Wkvd  = (const float*)d_in[3];
  const float* Wqd   = (const float*)d_in[4];
  const float* kvnw  = (const float*)d_in[5];
  const float* qnw   = (const float*)d_in[6];
  const float* Wkvup = (const float*)d_in[7];
  const float* Wqup  = (const float*)d_in[8];
  const float* lk1   = (const float*)d_in[9];
  const float* lk2   = (const float*)d_in[10];
  const float* lq1   = (const float*)d_in[11];
  const float* lq2   = (const float*)d_in[12];
  const float* normw = (const float*)d_in[13];
  const float* Wo    = (const float*)d_in[14];
  float* out = (float*)d_out;

  float* ws = (float*)d_ws;
  float* c      = ws;                       // S*288
  float* ckv    = c    + (size_t)S * 288;   // S*256
  float* cqr    = ckv  + (size_t)S * 256;   // S*384
  float* cq     = cqr  + (size_t)S * 384;   // S*384
  float* kvbuf  = cq   + (size_t)S * 384;   // S*2048
  float* qp     = kvbuf+ (size_t)S * 2048;  // S*1536
  float* qfT    = qp   + (size_t)S * 1536;  // 32*48*S
  float* kfT    = qfT  + (size_t)H2 * QKD * S;  // 32*48*S
  float* vv     = kfT  + (size_t)H2 * QKD * S;  // 16*S*64
  float* mbuf   = vv   + (size_t)NH * S * 64;   // 32*S
  float* rdbuf  = mbuf + (size_t)H2 * S;    // 32*S
  float* gbuf   = rdbuf+ (size_t)H2 * S;    // 16*S
  float* gvc    = gbuf + (size_t)NH * S;    // 16*S*64
  float* normed = gvc  + (size_t)NH * S * 64;   // S*1024
  float* lam    = normed + (size_t)S * D;   // 1

  // 1. down-projections
  gemm_f32<<<dim3(3, S / 128), 256, 0, stream>>>(x, Wkvd, c, S, D, 288);
  gemm_f32<<<dim3(3, S / 128), 256, 0, stream>>>(x, Wqd, cqr, S, D, 384);
  // 2. rmsnorms
  rmsnorm_rows<<<S, 256, 0, stream>>>(c, kvnw, ckv, 288, 256);
  rmsnorm_rows<<<S, 256, 0, stream>>>(cqr, qnw, cq, 384, 384);
  // 3. up-projections
  gemm_f32<<<dim3(16, S / 128), 256, 0, stream>>>(ckv, Wkvup, kvbuf, S, 256, 2048);
  gemm_f32<<<dim3(12, S / 128), 256, 0, stream>>>(cq, Wqup, qp, S, 384, 1536);
  // 4. assemble heads with RoPE
  assemble_qk<<<dim3(H2, S / 64), 64, 0, stream>>>(qp, kvbuf, c, freqs, qfT, kfT);
  assemble_v<<<(NH * S * 64) / 256, 256, 0, stream>>>(kvbuf, vv);
  compute_lam<<<1, 64, 0, stream>>>(lk1, lk2, lq1, lq2, lam);
  // 5. attention passes (triangular pairing: block p handles tiles p and 31-p)
  attn_md<<<dim3(16, H2), 256, 0, stream>>>(qfT, kfT, mbuf, rdbuf);
  attn_g<<<dim3(16, NH), 256, 0, stream>>>(qfT, kfT, mbuf, rdbuf, gbuf);
  attn_gvc<<<NH, 64, 0, stream>>>(gbuf, vv, gvc);
  attn_out<<<dim3(16, NH), 256, 0, stream>>>(qfT, kfT, vv, mbuf, rdbuf, gvc, lam, normw, normed);
  // 6. output projection
  gemm_f32<<<dim3(8, S / 128), 256, 0, stream>>>(normed, Wo, out, S, D, D);
}

// Round 3
// 1774.010 us; speedup vs baseline: 5.5740x; 5.5740x over previous
//
#include <hip/hip_runtime.h>
#include <hip/hip_bf16.h>
#include <math.h>

// Problem constants
constexpr int S    = 2048;
constexpr int D    = 1024;
constexpr int NH   = 16;
constexpr int HD   = 64;
constexpr int RD   = 32;
constexpr int KVC  = 256;
constexpr int QC   = 384;
constexpr int H2   = 32;      // 2*NH half-heads
constexpr int QKD  = 48;      // HD/2 + RD/2
constexpr float SCALE    = 0.14433756729740643f;  // 48^-0.5
constexpr float LAM_INIT = 0.2f;                  // 0.8 - 0.6*exp(0)
constexpr float EPS      = 1e-5f;

// balanced tile order: 0,31,1,30,2,29,... consecutive pairs sum to 33 steps
__device__ __forceinline__ int tile_order(int x) {
  return (x & 1) ? (31 - (x >> 1)) : (x >> 1);
}

// ---------------------------------------------------------------- GEMM (f32)
// C[M,N] = A[M,K] @ B[K,N]. 128x128 tile, BK=16, 256 threads, 8x8 per thread.
__global__ __launch_bounds__(256) void gemm_f32(
    const float* __restrict__ A, const float* __restrict__ B,
    float* __restrict__ C, int M, int K, int N) {
  __shared__ float As[16][128];
  __shared__ float Bs[16][128];
  const int tid = threadIdx.x;
  const int m0 = blockIdx.y * 128, n0 = blockIdx.x * 128;
  const int ty = tid >> 4, tx = tid & 15;
  float acc[8][8] = {};
  for (int k0 = 0; k0 < K; k0 += 16) {
#pragma unroll
    for (int it = 0; it < 2; ++it) {
      const int am = (tid >> 2) + it * 64;
      const int ak = (tid & 3) * 4;
      float4 a4 = *(const float4*)&A[(size_t)(m0 + am) * K + k0 + ak];
      As[ak + 0][am] = a4.x; As[ak + 1][am] = a4.y;
      As[ak + 2][am] = a4.z; As[ak + 3][am] = a4.w;
    }
#pragma unroll
    for (int it = 0; it < 2; ++it) {
      const int bk = (tid >> 5) + it * 8;
      const int bn = (tid & 31) * 4;
      const int gn = n0 + bn;
      float4 b4 = make_float4(0.f, 0.f, 0.f, 0.f);
      if (gn < N) b4 = *(const float4*)&B[(size_t)(k0 + bk) * N + gn];
      *(float4*)&Bs[bk][bn] = b4;
    }
    __syncthreads();
#pragma unroll
    for (int kk = 0; kk < 16; ++kk) {
      float a[8], b[8];
      *(float4*)&a[0] = *(const float4*)&As[kk][ty * 8];
      *(float4*)&a[4] = *(const float4*)&As[kk][ty * 8 + 4];
      *(float4*)&b[0] = *(const float4*)&Bs[kk][tx * 8];
      *(float4*)&b[4] = *(const float4*)&Bs[kk][tx * 8 + 4];
#pragma unroll
      for (int r = 0; r < 8; ++r)
#pragma unroll
        for (int c = 0; c < 8; ++c) acc[r][c] += a[r] * b[c];
    }
    __syncthreads();
  }
#pragma unroll
  for (int r = 0; r < 8; ++r) {
    const int gm = m0 + ty * 8 + r;
#pragma unroll
    for (int c4 = 0; c4 < 2; ++c4) {
      const int gn = n0 + tx * 8 + c4 * 4;
      if (gn < N) {
        float4 v = make_float4(acc[r][c4 * 4], acc[r][c4 * 4 + 1],
                               acc[r][c4 * 4 + 2], acc[r][c4 * 4 + 3]);
        *(float4*)&C[(size_t)gm * N + gn] = v;
      }
    }
  }
}

// ------------------------------------------------------------ row rmsnorm
__global__ __launch_bounds__(256) void rmsnorm_rows(
    const float* __restrict__ in, const float* __restrict__ w,
    float* __restrict__ out, int stride_in, int width) {
  const int row = blockIdx.x;
  const float* x = in + (size_t)row * stride_in;
  float ss = 0.f;
  for (int j = threadIdx.x; j < width; j += 256) { float v = x[j]; ss += v * v; }
  __shared__ float red[256];
  red[threadIdx.x] = ss;
  __syncthreads();
  for (int o = 128; o; o >>= 1) {
    if (threadIdx.x < o) red[threadIdx.x] += red[threadIdx.x + o];
    __syncthreads();
  }
  const float sc = rsqrtf(red[0] / (float)width + EPS);
  for (int j = threadIdx.x; j < width; j += 256)
    out[(size_t)row * width + j] = x[j] * sc * w[j];
}

// ------------------------------------------- assemble q_f^T, k_f^T with RoPE
// qfT/kfT layout: [h2][48][S]
__global__ __launch_bounds__(64) void assemble_qk(
    const float* __restrict__ qp, const float* __restrict__ kv,
    const float* __restrict__ c, const float* __restrict__ freqs,
    float* __restrict__ qfT, float* __restrict__ kfT) {
  const int h2 = blockIdx.x;
  const int s = blockIdx.y * 64 + threadIdx.x;
  const int m = h2 >> 1, e = h2 & 1;
  const int sp = s >> 2;  // s = sp*NSEQ + ns, NSEQ=4
  float cs[8], sn[8];
  if (sp > 0) {
#pragma unroll
    for (int t = 0; t < 8; ++t) {
      float a = freqs[(sp - 1) * 8 + t];
      cs[t] = cosf(a); sn[t] = sinf(a);
    }
  }
  // ---- q
  const float* qrow = qp + (size_t)s * (NH * (HD + RD)) + m * (HD + RD);
#pragma unroll
  for (int j = 0; j < 32; ++j)
    qfT[((size_t)(h2 * QKD + j)) * S + s] = qrow[e * 32 + j];
  float r[16];
#pragma unroll
  for (int j = 0; j < 16; ++j) r[j] = qrow[HD + e * 16 + j];
  if (sp > 0) {
#pragma unroll
    for (int t = 0; t < 8; ++t) {
      float a = r[2 * t], b = r[2 * t + 1];
      r[2 * t]     = a * cs[t] - b * sn[t];
      r[2 * t + 1] = a * sn[t] + b * cs[t];
    }
  }
#pragma unroll
  for (int j = 0; j < 16; ++j)
    qfT[((size_t)(h2 * QKD + 32 + j)) * S + s] = r[j];
  // ---- k
  const float* krow = kv + (size_t)s * (NH * 2 * HD) + m * (2 * HD);
#pragma unroll
  for (int j = 0; j < 32; ++j)
    kfT[((size_t)(h2 * QKD + j)) * S + s] = krow[e * 32 + j];
#pragma unroll
  for (int j = 0; j < 16; ++j)
    r[j] = c[(size_t)s * (KVC + RD) + KVC + e * 16 + j];
  if (sp > 0) {
#pragma unroll
    for (int t = 0; t < 8; ++t) {
      float a = r[2 * t], b = r[2 * t + 1];
      r[2 * t]     = a * cs[t] - b * sn[t];
      r[2 * t + 1] = a * sn[t] + b * cs[t];
    }
  }
#pragma unroll
  for (int j = 0; j < 16; ++j)
    kfT[((size_t)(h2 * QKD + 32 + j)) * S + s] = r[j];
}

// v layout [h][S][64]
__global__ __launch_bounds__(256) void assemble_v(
    const float* __restrict__ kv, float* __restrict__ vv) {
  const int i = blockIdx.x * 256 + threadIdx.x;  // < 16*2048*64
  const int dd = i & 63;
  const int s = (i >> 6) & (S - 1);
  const int h = i >> 17;
  vv[i] = kv[(size_t)s * (NH * 2 * HD) + h * (2 * HD) + HD + dd];
}

// lam scalar
__global__ __launch_bounds__(64) void compute_lam(
    const float* __restrict__ lk1, const float* __restrict__ lk2,
    const float* __restrict__ lq1, const float* __restrict__ lq2,
    float* __restrict__ lam) {
  const int t = threadIdx.x;
  float p1 = (t < 32) ? lk1[t] * lq1[t] : 0.f;
  float p2 = (t < 32) ? lk2[t] * lq2[t] : 0.f;
  for (int o = 16; o; o >>= 1) {
    p1 += __shfl_down(p1, o);
    p2 += __shfl_down(p2, o);
  }
  if (t == 0) *lam = expf(p1) - expf(p2) + LAM_INIT;
}

// 64x64x48 score tile: s[r][c] += sum_j Q[j][ty*4+r] * Kt[j][tx*4+c]
// partial unroll to bound register pressure (no load-hoist explosion)
__device__ __forceinline__ void score_gemm(
    const float (*__restrict__ Q)[64], const float (*__restrict__ Kt)[64],
    int ty, int tx, float s[4][4]) {
#pragma unroll 8
  for (int j = 0; j < QKD; ++j) {
    float4 a4 = *(const float4*)&Q[j][ty * 4];
    float4 b4 = *(const float4*)&Kt[j][tx * 4];
    const float a[4] = {a4.x, a4.y, a4.z, a4.w};
    const float b[4] = {b4.x, b4.y, b4.z, b4.w};
#pragma unroll
    for (int r = 0; r < 4; ++r)
#pragma unroll
      for (int c = 0; c < 4; ++c) s[r][c] += a[r] * b[c];
  }
}

// ------------------------------------------ Pass A: per-row max + 1/denom
// grid (32 q-tiles in balanced order, 32 h2)
__global__ __launch_bounds__(256) void attn_md(
    const float* __restrict__ qfT, const float* __restrict__ kfT,
    float* __restrict__ mOut, float* __restrict__ rdOut) {
  const int tile = tile_order(blockIdx.x), h2 = blockIdx.y;
  const int q0 = tile * 64;
  __shared__ float Qs[QKD][64], Ks[QKD][64];
  __shared__ float sm[64][17], sd[64][17];
  const int tid = threadIdx.x, ty = tid >> 4, tx = tid & 15;
  for (int idx = tid; idx < QKD * 64; idx += 256) {
    const int j = idx >> 6, qi = idx & 63;
    Qs[j][qi] = qfT[((size_t)(h2 * QKD + j)) * S + q0 + qi];
  }
  float ml[4] = {-1e30f, -1e30f, -1e30f, -1e30f};
  float dl[4] = {0.f, 0.f, 0.f, 0.f};
  __syncthreads();
  for (int k0 = 0; k0 <= q0; k0 += 64) {
    for (int idx = tid; idx < QKD * 64; idx += 256) {
      const int j = idx >> 6, ki = idx & 63;
      Ks[j][ki] = kfT[((size_t)(h2 * QKD + j)) * S + k0 + ki];
    }
    __syncthreads();
    float s[4][4] = {};
    score_gemm(Qs, Ks, ty, tx, s);
    const bool diag = (k0 == q0);
#pragma unroll
    for (int r = 0; r < 4; ++r) {
      float av[4];
      float tm = ml[r];
#pragma unroll
      for (int c = 0; c < 4; ++c) {
        av[c] = fabsf(s[r][c] * SCALE);
        const bool valid = !diag || (tx * 4 + c <= ty * 4 + r);
        if (valid) tm = fmaxf(tm, av[c]);
      }
      float add = 0.f;
#pragma unroll
      for (int c = 0; c < 4; ++c) {
        const bool valid = !diag || (tx * 4 + c <= ty * 4 + r);
        if (valid) add += expf(av[c] - tm);
      }
      dl[r] = dl[r] * expf(ml[r] - tm) + add;
      ml[r] = tm;
    }
    __syncthreads();
  }
#pragma unroll
  for (int r = 0; r < 4; ++r) { sm[ty * 4 + r][tx] = ml[r]; sd[ty * 4 + r][tx] = dl[r]; }
  __syncthreads();
  if (tid < 64) {
    float M = -1e30f;
#pragma unroll
    for (int t = 0; t < 16; ++t) M = fmaxf(M, sm[tid][t]);
    float Dd = 0.f;
#pragma unroll
    for (int t = 0; t < 16; ++t) Dd += sd[tid][t] * expf(sm[tid][t] - M);
    mOut[h2 * S + q0 + tid] = M;
    rdOut[h2 * S + q0 + tid] = 1.0f / Dd;
  }
}

// ---------------- Pass B: gpart[z][h][k] = sum over q-chunk z of p1[q,k]
// grid (32 k-tiles balanced order, 16 h, 2 q-chunks)
__global__ __launch_bounds__(256) void attn_g(
    const float* __restrict__ qfT, const float* __restrict__ kfT,
    const float* __restrict__ mIn, const float* __restrict__ rdIn,
    float* __restrict__ gpart) {
  const int tile = tile_order(blockIdx.x), h = blockIdx.y, z = blockIdx.z;
  const int h2 = 2 * h;
  const int k0 = tile * 64;
  __shared__ float Ks[QKD][64], Qs[QKD][64];
  __shared__ float mq[64], rq[64];
  __shared__ float red[64][17];
  const int tid = threadIdx.x, ty = tid >> 4, tx = tid & 15;
  for (int idx = tid; idx < QKD * 64; idx += 256) {
    const int j = idx >> 6, ki = idx & 63;
    Ks[j][ki] = kfT[((size_t)(h2 * QKD + j)) * S + k0 + ki];
  }
  float acc[4] = {0.f, 0.f, 0.f, 0.f};
  __syncthreads();
  for (int qt = tile + z; qt < 32; qt += 2) {
    const int q0 = qt * 64;
    for (int idx = tid; idx < QKD * 64; idx += 256) {
      const int j = idx >> 6, qi = idx & 63;
      Qs[j][qi] = qfT[((size_t)(h2 * QKD + j)) * S + q0 + qi];
    }
    if (tid < 64) {
      mq[tid] = mIn[h2 * S + q0 + tid];
      rq[tid] = rdIn[h2 * S + q0 + tid];
    }
    __syncthreads();
    float s[4][4] = {};
    score_gemm(Qs, Ks, ty, tx, s);
    const bool diag = (q0 == k0);
#pragma unroll
    for (int r = 0; r < 4; ++r) {
      const float mv = mq[ty * 4 + r], rv = rq[ty * 4 + r];
#pragma unroll
      for (int c = 0; c < 4; ++c) {
        const bool valid = !diag || (ty * 4 + r >= tx * 4 + c);
        if (valid) {
          const float sv = s[r][c] * SCALE;
          const float av = fabsf(sv);
          const float sg = (sv > 0.f) ? 1.f : ((sv < 0.f) ? -1.f : 0.f);
          acc[c] += sg * expf(av - mv) * rv;
        }
      }
    }
    __syncthreads();
  }
#pragma unroll
  for (int c = 0; c < 4; ++c) red[tx * 4 + c][ty] = acc[c];
  __syncthreads();
  if (tid < 64) {
    float sum = 0.f;
#pragma unroll
    for (int t = 0; t < 16; ++t) sum += red[tid][t];
    gpart[((size_t)(z * NH + h)) * S + k0 + tid] = sum;
  }
}

// g = (gpart0 + gpart1) / S
__global__ __launch_bounds__(256) void g_reduce(
    const float* __restrict__ gpart, float* __restrict__ g) {
  const int i = blockIdx.x * 256 + threadIdx.x;  // < NH*S
  g[i] = (gpart[i] + gpart[(size_t)NH * S + i]) * (1.0f / (float)S);
}

// --------------------------- Pass C: prefix sum over k of g[h,k]*v[h,k,dd]
__global__ __launch_bounds__(64) void attn_gvc(
    const float* __restrict__ g, const float* __restrict__ vv,
    float* __restrict__ gvc) {
  const int h = blockIdx.x, dd = threadIdx.x;
  float run = 0.f;
#pragma unroll 4
  for (int k = 0; k < S; ++k) {
    run += g[h * S + k] * vv[((size_t)(h * S + k)) * 64 + dd];
    gvc[((size_t)(h * S + k)) * 64 + dd] = run;
  }
}

// --------------- Pass D: out = (p1 - lam*p2)@V + lam*gvc ; fused rmsnorm
// grid (32 q-tiles balanced order, 16 h). One score acc live at a time.
__global__ __launch_bounds__(256) void attn_out(
    const float* __restrict__ qfT, const float* __restrict__ kfT,
    const float* __restrict__ vv, const float* __restrict__ mIn,
    const float* __restrict__ rdIn, const float* __restrict__ gvc,
    const float* __restrict__ lamPtr, const float* __restrict__ normW,
    float* __restrict__ normed) {
  const int tile = tile_order(blockIdx.x), h = blockIdx.y;
  const int q0 = tile * 64;
  const int h2a = 2 * h, h2b = 2 * h + 1;
  __shared__ float Q1[QKD][64], Q2[QKD][64];
  __shared__ float Ps[64][68];   // P tile, padded
  __shared__ float KV[64 * 64];  // K tile [48][64] then V tile [64][64]
  __shared__ float m1s[64], r1s[64], m2s[64], r2s[64];
  __shared__ float rn[64][17];
  __shared__ float rs[64];
  const int tid = threadIdx.x, ty = tid >> 4, tx = tid & 15;
  const float lam = *lamPtr;
  for (int idx = tid; idx < QKD * 64; idx += 256) {
    const int j = idx >> 6, qi = idx & 63;
    Q1[j][qi] = qfT[((size_t)(h2a * QKD + j)) * S + q0 + qi];
    Q2[j][qi] = qfT[((size_t)(h2b * QKD + j)) * S + q0 + qi];
  }
  if (tid < 64) {
    m1s[tid] = mIn[h2a * S + q0 + tid];
    r1s[tid] = rdIn[h2a * S + q0 + tid];
    m2s[tid] = mIn[h2b * S + q0 + tid];
    r2s[tid] = rdIn[h2b * S + q0 + tid];
  }
  float out[4][4] = {};
  __syncthreads();
  for (int k0 = 0; k0 <= q0; k0 += 64) {
    const bool diag = (k0 == q0);
    // ---- K1 -> Ps = p1
    for (int idx = tid; idx < QKD * 64; idx += 256) {
      const int j = idx >> 6, ki = idx & 63;
      KV[j * 64 + ki] = kfT[((size_t)(h2a * QKD + j)) * S + k0 + ki];
    }
    __syncthreads();
    {
      float s[4][4] = {};
      score_gemm(Q1, (const float(*)[64])KV, ty, tx, s);
#pragma unroll
      for (int r = 0; r < 4; ++r) {
        const int row = ty * 4 + r;
        const float m1 = m1s[row], rd1 = r1s[row];
#pragma unroll
        for (int c = 0; c < 4; ++c) {
          float p = 0.f;
          const bool valid = !diag || (tx * 4 + c <= row);
          if (valid) {
            const float v1 = s[r][c] * SCALE;
            const float sg1 = (v1 > 0.f) ? 1.f : ((v1 < 0.f) ? -1.f : 0.f);
            p = sg1 * expf(fabsf(v1) - m1) * rd1;
          }
          Ps[row][tx * 4 + c] = p;
        }
      }
    }
    __syncthreads();
    // ---- K2 -> Ps -= lam*p2
    for (int idx = tid; idx < QKD * 64; idx += 256) {
      const int j = idx >> 6, ki = idx & 63;
      KV[j * 64 + ki] = kfT[((size_t)(h2b * QKD + j)) * S + k0 + ki];
    }
    __syncthreads();
    {
      float s[4][4] = {};
      score_gemm(Q2, (const float(*)[64])KV, ty, tx, s);
#pragma unroll
      for (int r = 0; r < 4; ++r) {
        const int row = ty * 4 + r;
        const float m2 = m2s[row], rd2 = r2s[row];
#pragma unroll
        for (int c = 0; c < 4; ++c) {
          const bool valid = !diag || (tx * 4 + c <= row);
          if (valid) {
            const float v2 = s[r][c] * SCALE;
            const float sg2 = (v2 > 0.f) ? 1.f : ((v2 < 0.f) ? -1.f : 0.f);
            Ps[row][tx * 4 + c] -= lam * (sg2 * expf(fabsf(v2) - m2) * rd2);
          }
        }
      }
    }
    __syncthreads();
    // ---- V tile
    for (int idx = tid; idx < 64 * 64; idx += 256) {
      const int ki = idx >> 6, dd = idx & 63;
      KV[ki * 64 + dd] = vv[((size_t)(h * S + k0 + ki)) * 64 + dd];
    }
    __syncthreads();
    // ---- PV
#pragma unroll 4
    for (int kq = 0; kq < 16; ++kq) {
      float pa[4][4];
#pragma unroll
      for (int r = 0; r < 4; ++r)
        *(float4*)pa[r] = *(const float4*)&Ps[ty * 4 + r][kq * 4];
#pragma unroll
      for (int u = 0; u < 4; ++u) {
        float4 b4 = *(const float4*)&KV[(kq * 4 + u) * 64 + tx * 4];
        const float b[4] = {b4.x, b4.y, b4.z, b4.w};
#pragma unroll
        for (int r = 0; r < 4; ++r)
#pragma unroll
          for (int c = 0; c < 4; ++c) out[r][c] += pa[r][u] * b[c];
      }
    }
    __syncthreads();
  }
  // epilogue: + lam*gvc, fused rmsnorm, store
#pragma unroll
  for (int r = 0; r < 4; ++r) {
    const int row = ty * 4 + r;
    float ss = 0.f;
#pragma unroll
    for (int c = 0; c < 4; ++c) {
      const float val = out[r][c]
          + lam * gvc[((size_t)(h * S + q0 + row)) * 64 + tx * 4 + c];
      out[r][c] = val;
      ss += val * val;
    }
    rn[row][tx] = ss;
  }
  __syncthreads();
  if (tid < 64) {
    float tot = 0.f;
#pragma unroll
    for (int t = 0; t < 16; ++t) tot += rn[tid][t];
    rs[tid] = rsqrtf(tot * (1.0f / 64.0f) + EPS);
  }
  __syncthreads();
#pragma unroll
  for (int r = 0; r < 4; ++r) {
    const int row = ty * 4 + r;
    const float sc = rs[row];
#pragma unroll
    for (int c = 0; c < 4; ++c) {
      const int dd = tx * 4 + c;
      normed[(size_t)(q0 + row) * D + h * 64 + dd] = out[r][c] * sc * normW[dd];
    }
  }
}

// ----------------------------------------------------------------- launch
extern "C" void kernel_launch(void* const* d_in, const int* in_sizes, int n_in,
                              void* d_out, int out_size, void* d_ws, size_t ws_size,
                              hipStream_t stream) {
  const float* x     = (const float*)d_in[0];
  // d_in[1] = mask (causal triu, recomputed implicitly)
  const float* freqs = (const float*)d_in[2];
  const float* Wkvd  = (const float*)d_in[3];
  const float* Wqd   = (const float*)d_in[4];
  const float* kvnw  = (const float*)d_in[5];
  const float* qnw   = (const float*)d_in[6];
  const float* Wkvup = (const float*)d_in[7];
  const float* Wqup  = (const float*)d_in[8];
  const float* lk1   = (const float*)d_in[9];
  const float* lk2   = (const float*)d_in[10];
  const float* lq1   = (const float*)d_in[11];
  const float* lq2   = (const float*)d_in[12];
  const float* normw = (const float*)d_in[13];
  const float* Wo    = (const float*)d_in[14];
  float* out = (float*)d_out;

  float* ws = (float*)d_ws;
  float* c      = ws;                       // S*288
  float* ckv    = c    + (size_t)S * 288;   // S*256
  float* cqr    = ckv  + (size_t)S * 256;   // S*384
  float* cq     = cqr  + (size_t)S * 384;   // S*384
  float* kvbuf  = cq   + (size_t)S * 384;   // S*2048
  float* qp     = kvbuf+ (size_t)S * 2048;  // S*1536
  float* qfT    = qp   + (size_t)S * 1536;  // 32*48*S
  float* kfT    = qfT  + (size_t)H2 * QKD * S;  // 32*48*S
  float* vv     = kfT  + (size_t)H2 * QKD * S;  // 16*S*64
  float* mbuf   = vv   + (size_t)NH * S * 64;   // 32*S
  float* rdbuf  = mbuf + (size_t)H2 * S;    // 32*S
  float* gbuf   = rdbuf+ (size_t)H2 * S;    // 16*S
  float* gpart  = gbuf + (size_t)NH * S;    // 2*16*S
  float* gvc    = gpart+ (size_t)2 * NH * S;    // 16*S*64
  float* normed = gvc  + (size_t)NH * S * 64;   // S*1024
  float* lam    = normed + (size_t)S * D;   // 1

  // 1. down-projections
  gemm_f32<<<dim3(3, S / 128), 256, 0, stream>>>(x, Wkvd, c, S, D, 288);
  gemm_f32<<<dim3(3, S / 128), 256, 0, stream>>>(x, Wqd, cqr, S, D, 384);
  // 2. rmsnorms
  rmsnorm_rows<<<S, 256, 0, stream>>>(c, kvnw, ckv, 288, 256);
  rmsnorm_rows<<<S, 256, 0, stream>>>(cqr, qnw, cq, 384, 384);
  // 3. up-projections
  gemm_f32<<<dim3(16, S / 128), 256, 0, stream>>>(ckv, Wkvup, kvbuf, S, 256, 2048);
  gemm_f32<<<dim3(12, S / 128), 256, 0, stream>>>(cq, Wqup, qp, S, 384, 1536);
  // 4. assemble heads with RoPE
  assemble_qk<<<dim3(H2, S / 64), 64, 0, stream>>>(qp, kvbuf, c, freqs, qfT, kfT);
  assemble_v<<<(NH * S * 64) / 256, 256, 0, stream>>>(kvbuf, vv);
  compute_lam<<<1, 64, 0, stream>>>(lk1, lk2, lq1, lq2, lam);
  // 5. attention passes
  attn_md<<<dim3(32, H2), 256, 0, stream>>>(qfT, kfT, mbuf, rdbuf);
  attn_g<<<dim3(32, NH, 2), 256, 0, stream>>>(qfT, kfT, mbuf, rdbuf, gpart);
  g_reduce<<<(NH * S) / 256, 256, 0, stream>>>(gpart, gbuf);
  attn_gvc<<<NH, 64, 0, stream>>>(gbuf, vv, gvc);
  attn_out<<<dim3(32, NH), 256, 0, stream>>>(qfT, kfT, vv, mbuf, rdbuf, gvc, lam, normw, normed);
  // 6. output projection
  gemm_f32<<<dim3(8, S / 128), 256, 0, stream>>>(normed, Wo, out, S, D, D);
}

// Round 7
// 1381.120 us; speedup vs baseline: 7.1597x; 1.2845x over previous
//
#include <hip/hip_runtime.h>
#include <hip/hip_bf16.h>
#include <math.h>

// Problem constants
constexpr int S    = 2048;
constexpr int D    = 1024;
constexpr int NH   = 16;
constexpr int H2   = 32;      // 2*NH half-heads
constexpr int QKD  = 48;      // HD/2 + RD/2
constexpr int QKP  = 56;      // padded LDS k-stride (112B, 16B-aligned rows)
constexpr float SCALE    = 0.14433756729740643f;  // 48^-0.5
constexpr float LAM_INIT = 0.2f;                  // 0.8 - 0.6*exp(0)
constexpr float EPS      = 1e-5f;

typedef __attribute__((ext_vector_type(8)))  short bf16x8;
typedef __attribute__((ext_vector_type(16))) float f32x16;

__device__ __forceinline__ int tile_order(int x) {
  return (x & 1) ? (31 - (x >> 1)) : (x >> 1);
}
__device__ __forceinline__ short f2bf(float x) {
  union { float f; unsigned u; } v; v.f = x;
  unsigned r = v.u + 0x7FFFu + ((v.u >> 16) & 1u);   // round-to-nearest-even
  return (short)(r >> 16);
}
__device__ __forceinline__ float bf2f(short b) {
  union { unsigned u; float f; } v; v.u = ((unsigned)(unsigned short)b) << 16;
  return v.f;
}
// D-fragment row pattern for mfma_f32_32x32x16: row=(reg&3)+8*(reg>>2)+4*(lane>>5)
__device__ __forceinline__ int d_rowpat(int r, int lane) {
  return (r & 3) + 8 * (r >> 2) + 4 * ((lane >> 5) & 1);
}
__device__ __forceinline__ f32x16 fzero16() {
  f32x16 z;
#pragma unroll
  for (int i = 0; i < 16; ++i) z[i] = 0.f;
  return z;
}
// A/B fragment from LDS tile [64 pos][QKP] bf16: lane holds pos=(lane&31)+32*sub,
// k = (lane>>5)*8 + 16*ks .. +7
__device__ __forceinline__ bf16x8 frag56(const short* t, int lane, int sub, int ks) {
  return *(const bf16x8*)(t + ((lane & 31) + 32 * sub) * QKP + ((lane >> 5) << 3) + 16 * ks);
}
__device__ __forceinline__ bf16x8 frag72(const short* t, int lane, int sub, int ks) {
  return *(const bf16x8*)(t + ((lane & 31) + 32 * sub) * 72 + ((lane >> 5) << 3) + 16 * ks);
}
// split-bf16 score: D = Ahi*Bhi + Ahi*Blo + Alo*Bhi over K=48 (3 k-steps)
__device__ __forceinline__ f32x16 score_mfma(
    const short* ah, const short* al, const short* bh, const short* bl,
    int lane, int asub, int bsub) {
  f32x16 acc = fzero16();
#pragma unroll
  for (int t = 0; t < 3; ++t) {
    bf16x8 xh = frag56(ah, lane, asub, t);
    bf16x8 yh = frag56(bh, lane, bsub, t);
    bf16x8 xl = frag56(al, lane, asub, t);
    bf16x8 yl = frag56(bl, lane, bsub, t);
    acc = __builtin_amdgcn_mfma_f32_32x32x16_bf16(xh, yh, acc, 0, 0, 0);
    acc = __builtin_amdgcn_mfma_f32_32x32x16_bf16(xh, yl, acc, 0, 0, 0);
    acc = __builtin_amdgcn_mfma_f32_32x32x16_bf16(xl, yh, acc, 0, 0, 0);
  }
  return acc;
}
// stage a 64x48-bf16 tile (global unpadded, 24 u32/row) into LDS (28 u32/row)
__device__ __forceinline__ void stage_tile(const unsigned* __restrict__ g,
                                           unsigned* __restrict__ lds, int tid) {
  for (int i = tid; i < 64 * 24; i += 256) {
    const int r = i / 24, c = i - r * 24;
    lds[r * 28 + c] = g[r * 24 + c];
  }
}
__device__ __forceinline__ float signedp(float sv, float mrow, float rrow) {
  const float e = __expf(fabsf(sv) - mrow) * rrow;
  return (sv > 0.f) ? e : ((sv < 0.f) ? -e : 0.f);
}

// ---------------------------------------------------------------- GEMM (f32)
__global__ __launch_bounds__(256) void gemm_f32(
    const float* __restrict__ A, const float* __restrict__ B,
    float* __restrict__ C, int M, int K, int N) {
  __shared__ float As[16][128];
  __shared__ float Bs[16][128];
  const int tid = threadIdx.x;
  const int m0 = blockIdx.y * 128, n0 = blockIdx.x * 128;
  const int ty = tid >> 4, tx = tid & 15;
  float acc[8][8] = {};
  for (int k0 = 0; k0 < K; k0 += 16) {
#pragma unroll
    for (int it = 0; it < 2; ++it) {
      const int am = (tid >> 2) + it * 64;
      const int ak = (tid & 3) * 4;
      float4 a4 = *(const float4*)&A[(size_t)(m0 + am) * K + k0 + ak];
      As[ak + 0][am] = a4.x; As[ak + 1][am] = a4.y;
      As[ak + 2][am] = a4.z; As[ak + 3][am] = a4.w;
    }
#pragma unroll
    for (int it = 0; it < 2; ++it) {
      const int bk = (tid >> 5) + it * 8;
      const int bn = (tid & 31) * 4;
      const int gn = n0 + bn;
      float4 b4 = make_float4(0.f, 0.f, 0.f, 0.f);
      if (gn < N) b4 = *(const float4*)&B[(size_t)(k0 + bk) * N + gn];
      *(float4*)&Bs[bk][bn] = b4;
    }
    __syncthreads();
#pragma unroll
    for (int kk = 0; kk < 16; ++kk) {
      float a[8], b[8];
      *(float4*)&a[0] = *(const float4*)&As[kk][ty * 8];
      *(float4*)&a[4] = *(const float4*)&As[kk][ty * 8 + 4];
      *(float4*)&b[0] = *(const float4*)&Bs[kk][tx * 8];
      *(float4*)&b[4] = *(const float4*)&Bs[kk][tx * 8 + 4];
#pragma unroll
      for (int r = 0; r < 8; ++r)
#pragma unroll
        for (int c = 0; c < 8; ++c) acc[r][c] += a[r] * b[c];
    }
    __syncthreads();
  }
#pragma unroll
  for (int r = 0; r < 8; ++r) {
    const int gm = m0 + ty * 8 + r;
#pragma unroll
    for (int c4 = 0; c4 < 2; ++c4) {
      const int gn = n0 + tx * 8 + c4 * 4;
      if (gn < N) {
        float4 v = make_float4(acc[r][c4 * 4], acc[r][c4 * 4 + 1],
                               acc[r][c4 * 4 + 2], acc[r][c4 * 4 + 3]);
        *(float4*)&C[(size_t)gm * N + gn] = v;
      }
    }
  }
}

// ------------------------------------------------------------ row rmsnorm
__global__ __launch_bounds__(256) void rmsnorm_rows(
    const float* __restrict__ in, const float* __restrict__ w,
    float* __restrict__ out, int stride_in, int width) {
  const int row = blockIdx.x;
  const float* x = in + (size_t)row * stride_in;
  float ss = 0.f;
  for (int j = threadIdx.x; j < width; j += 256) { float v = x[j]; ss += v * v; }
  __shared__ float red[256];
  red[threadIdx.x] = ss;
  __syncthreads();
  for (int o = 128; o; o >>= 1) {
    if (threadIdx.x < o) red[threadIdx.x] += red[threadIdx.x + o];
    __syncthreads();
  }
  const float sc = rsqrtf(red[0] / (float)width + EPS);
  for (int j = threadIdx.x; j < width; j += 256)
    out[(size_t)row * width + j] = x[j] * sc * w[j];
}

// ---- assemble q/k with RoPE -> f32 [h2][48][S] + hi/lo bf16 [h2][S][48]
__global__ __launch_bounds__(64) void assemble_qk(
    const float* __restrict__ qp, const float* __restrict__ kv,
    const float* __restrict__ c, const float* __restrict__ freqs,
    float* __restrict__ qfT, float* __restrict__ kfT,
    short* __restrict__ qhi, short* __restrict__ qlo,
    short* __restrict__ khi, short* __restrict__ klo) {
  const int h2 = blockIdx.x, s0 = blockIdx.y * 64;
  const int tid = threadIdx.x, s = s0 + tid;
  const int m = h2 >> 1, e = h2 & 1;
  const int sp = s >> 2;
  float cs[8], sn[8];
  if (sp > 0) {
#pragma unroll
    for (int t = 0; t < 8; ++t) {
      float a = freqs[(sp - 1) * 8 + t];
      cs[t] = cosf(a); sn[t] = sinf(a);
    }
  }
  float v[48], rr[16];
  // ---- q
  {
    const float* qrow = qp + (size_t)s * (NH * 96) + m * 96;
#pragma unroll
    for (int j = 0; j < 32; ++j) v[j] = qrow[e * 32 + j];
#pragma unroll
    for (int j = 0; j < 16; ++j) rr[j] = qrow[64 + e * 16 + j];
    if (sp > 0) {
#pragma unroll
      for (int t = 0; t < 8; ++t) {
        float a = rr[2 * t], b = rr[2 * t + 1];
        rr[2 * t]     = a * cs[t] - b * sn[t];
        rr[2 * t + 1] = a * sn[t] + b * cs[t];
      }
    }
#pragma unroll
    for (int j = 0; j < 16; ++j) v[32 + j] = rr[j];
#pragma unroll
    for (int j = 0; j < 48; ++j) qfT[((size_t)(h2 * QKD + j)) * S + s] = v[j];
    unsigned* dh = (unsigned*)(qhi + ((size_t)h2 * S + s) * 48);
    unsigned* dl = (unsigned*)(qlo + ((size_t)h2 * S + s) * 48);
#pragma unroll
    for (int j = 0; j < 24; ++j) {
      const short h0 = f2bf(v[2 * j]),     h1 = f2bf(v[2 * j + 1]);
      const short l0 = f2bf(v[2 * j] - bf2f(h0));
      const short l1 = f2bf(v[2 * j + 1] - bf2f(h1));
      dh[j] = (unsigned)(unsigned short)h0 | ((unsigned)(unsigned short)h1 << 16);
      dl[j] = (unsigned)(unsigned short)l0 | ((unsigned)(unsigned short)l1 << 16);
    }
  }
  // ---- k
  {
    const float* krow = kv + (size_t)s * (NH * 128) + m * 128;
#pragma unroll
    for (int j = 0; j < 32; ++j) v[j] = krow[e * 32 + j];
#pragma unroll
    for (int j = 0; j < 16; ++j) rr[j] = c[(size_t)s * 288 + 256 + e * 16 + j];
    if (sp > 0) {
#pragma unroll
      for (int t = 0; t < 8; ++t) {
        float a = rr[2 * t], b = rr[2 * t + 1];
        rr[2 * t]     = a * cs[t] - b * sn[t];
        rr[2 * t + 1] = a * sn[t] + b * cs[t];
      }
    }
#pragma unroll
    for (int j = 0; j < 16; ++j) v[32 + j] = rr[j];
#pragma unroll
    for (int j = 0; j < 48; ++j) kfT[((size_t)(h2 * QKD + j)) * S + s] = v[j];
    unsigned* dh = (unsigned*)(khi + ((size_t)h2 * S + s) * 48);
    unsigned* dl = (unsigned*)(klo + ((size_t)h2 * S + s) * 48);
#pragma unroll
    for (int j = 0; j < 24; ++j) {
      const short h0 = f2bf(v[2 * j]),     h1 = f2bf(v[2 * j + 1]);
      const short l0 = f2bf(v[2 * j] - bf2f(h0));
      const short l1 = f2bf(v[2 * j + 1] - bf2f(h1));
      dh[j] = (unsigned)(unsigned short)h0 | ((unsigned)(unsigned short)h1 << 16);
      dl[j] = (unsigned)(unsigned short)l0 | ((unsigned)(unsigned short)l1 << 16);
    }
  }
}

// ---- V transposed bf16 hi/lo: vT*[h][d(64)][S]
__global__ __launch_bounds__(256) void assemble_v(
    const float* __restrict__ kv, short* __restrict__ vThi,
    short* __restrict__ vTlo) {
  const int h = blockIdx.x, s0 = blockIdx.y * 64;
  const int tid = threadIdx.x;
  __shared__ float t[64][65];
  for (int i = tid; i < 4096; i += 256) {
    const int sl = i >> 6, dd = i & 63;
    t[sl][dd] = kv[(size_t)(s0 + sl) * (NH * 128) + h * 128 + 64 + dd];
  }
  __syncthreads();
  for (int i = tid; i < 4096; i += 256) {
    const int dd = i >> 6, sl = i & 63;
    const float v = t[sl][dd];
    const short hi = f2bf(v);
    vThi[((size_t)(h * 64 + dd)) * S + s0 + sl] = hi;
    vTlo[((size_t)(h * 64 + dd)) * S + s0 + sl] = f2bf(v - bf2f(hi));
  }
}

// lam scalar
__global__ __launch_bounds__(64) void compute_lam(
    const float* __restrict__ lk1, const float* __restrict__ lk2,
    const float* __restrict__ lq1, const float* __restrict__ lq2,
    float* __restrict__ lam) {
  const int t = threadIdx.x;
  float p1 = (t < 32) ? lk1[t] * lq1[t] : 0.f;
  float p2 = (t < 32) ? lk2[t] * lq2[t] : 0.f;
  for (int o = 16; o; o >>= 1) {
    p1 += __shfl_down(p1, o);
    p2 += __shfl_down(p2, o);
  }
  if (t == 0) *lam = expf(p1) - expf(p2) + LAM_INIT;
}

// ------------------------------------------ Pass A: per-row max + 1/denom
// split-bf16 scores (|s| err ~5e-6 -> m,d effectively f32). A=K rows, B=Q cols.
__global__ __launch_bounds__(256) void attn_md(
    const short* __restrict__ qhi, const short* __restrict__ qlo,
    const short* __restrict__ khi, const short* __restrict__ klo,
    float* __restrict__ mOut, float* __restrict__ rdOut) {
  const int tile = tile_order(blockIdx.x), h2 = blockIdx.y;
  const int q0 = tile * 64;
  __shared__ __align__(16) short qh_s[64 * QKP], ql_s[64 * QKP];
  __shared__ __align__(16) short kh_s[64 * QKP], kl_s[64 * QKP];
  __shared__ float mpart[2][64], dpart[2][64];
  const int tid = threadIdx.x, lane = tid & 63, w = tid >> 6;
  const int asub = w >> 1, bsub = w & 1;
  stage_tile((const unsigned*)(qhi + ((size_t)h2 * S + q0) * 48), (unsigned*)qh_s, tid);
  stage_tile((const unsigned*)(qlo + ((size_t)h2 * S + q0) * 48), (unsigned*)ql_s, tid);
  float m_acc = -1e30f, d_acc = 0.f;
  const int qg = q0 + 32 * bsub + (lane & 31);
  for (int kt = 0; kt <= tile; ++kt) {
    __syncthreads();
    const int k0 = kt * 64;
    stage_tile((const unsigned*)(khi + ((size_t)h2 * S + k0) * 48), (unsigned*)kh_s, tid);
    stage_tile((const unsigned*)(klo + ((size_t)h2 * S + k0) * 48), (unsigned*)kl_s, tid);
    __syncthreads();
    f32x16 acc = score_mfma(kh_s, kl_s, qh_s, ql_s, lane, asub, bsub);
    float av[16];
    float tm = -1e30f;
    if (kt < tile) {
#pragma unroll
      for (int r = 0; r < 16; ++r) { av[r] = fabsf(acc[r] * SCALE); tm = fmaxf(tm, av[r]); }
    } else {
#pragma unroll
      for (int r = 0; r < 16; ++r) {
        const int kg = k0 + 32 * asub + d_rowpat(r, lane);
        av[r] = (kg <= qg) ? fabsf(acc[r] * SCALE) : -1e30f;
        tm = fmaxf(tm, av[r]);
      }
    }
    const float nm = fmaxf(m_acc, tm);
    if (nm > -1e29f) {
      float add = 0.f;
#pragma unroll
      for (int r = 0; r < 16; ++r) add += __expf(av[r] - nm);
      d_acc = d_acc * __expf(m_acc - nm) + add;
      m_acc = nm;
    }
  }
  {
    const float m2 = __shfl_xor(m_acc, 32);
    const float d2 = __shfl_xor(d_acc, 32);
    const float nm = fmaxf(m_acc, m2);
    float dd = 0.f;
    if (nm > -1e29f) dd = d_acc * __expf(m_acc - nm) + d2 * __expf(m2 - nm);
    if ((lane & 32) == 0) {
      mpart[asub][32 * bsub + (lane & 31)] = nm;
      dpart[asub][32 * bsub + (lane & 31)] = dd;
    }
  }
  __syncthreads();
  if (tid < 64) {
    const float ma = mpart[0][tid], mb = mpart[1][tid];
    const float da = dpart[0][tid], db = dpart[1][tid];
    const float mm = fmaxf(ma, mb);
    const float dsum = da * __expf(ma - mm) + db * __expf(mb - mm);
    mOut[h2 * S + q0 + tid] = mm;
    rdOut[h2 * S + q0 + tid] = 1.0f / dsum;
  }
}

// ------------------------------------------ Pass B: g[h][k] = mean_q p1[q,k]
// split-bf16 scores. A=Q rows, B=K cols.
__global__ __launch_bounds__(256) void attn_g(
    const short* __restrict__ qhi, const short* __restrict__ qlo,
    const short* __restrict__ khi, const short* __restrict__ klo,
    const float* __restrict__ mIn, const float* __restrict__ rdIn,
    float* __restrict__ g) {
  const int tile = tile_order(blockIdx.x), h = blockIdx.y, h2 = 2 * h;
  const int k0 = tile * 64;
  __shared__ __align__(16) short kh_s[64 * QKP], kl_s[64 * QKP];
  __shared__ __align__(16) short qh_s[64 * QKP], ql_s[64 * QKP];
  __shared__ float mq[64], rq[64];
  __shared__ float gpart[2][64];
  const int tid = threadIdx.x, lane = tid & 63, w = tid >> 6;
  const int qsub = w >> 1, ksub = w & 1;
  stage_tile((const unsigned*)(khi + ((size_t)h2 * S + k0) * 48), (unsigned*)kh_s, tid);
  stage_tile((const unsigned*)(klo + ((size_t)h2 * S + k0) * 48), (unsigned*)kl_s, tid);
  float acc_g = 0.f;
  const int kg = k0 + 32 * ksub + (lane & 31);
  for (int qt = tile; qt < 32; ++qt) {
    __syncthreads();
    const int q0 = qt * 64;
    stage_tile((const unsigned*)(qhi + ((size_t)h2 * S + q0) * 48), (unsigned*)qh_s, tid);
    stage_tile((const unsigned*)(qlo + ((size_t)h2 * S + q0) * 48), (unsigned*)ql_s, tid);
    if (tid < 64) { mq[tid] = mIn[h2 * S + q0 + tid]; rq[tid] = rdIn[h2 * S + q0 + tid]; }
    __syncthreads();
    f32x16 acc = score_mfma(qh_s, ql_s, kh_s, kl_s, lane, qsub, ksub);
    const bool dg = (qt == tile);
#pragma unroll
    for (int r = 0; r < 16; ++r) {
      const int row = d_rowpat(r, lane) + 32 * qsub;
      if (!dg || (q0 + row) >= kg) {
        const float sv = acc[r] * SCALE;
        acc_g += signedp(sv, mq[row], rq[row]);
      }
    }
  }
  acc_g += __shfl_xor(acc_g, 32);
  if ((lane & 32) == 0) gpart[qsub][32 * ksub + (lane & 31)] = acc_g;
  __syncthreads();
  if (tid < 64)
    g[h * S + k0 + tid] = (gpart[0][tid] + gpart[1][tid]) * (1.0f / (float)S);
}

// --------------------------- Pass C: prefix sum over k of g[h,k]*v[h,k,dd]
__global__ __launch_bounds__(64) void attn_gvc(
    const float* __restrict__ g, const short* __restrict__ vThi,
    const short* __restrict__ vTlo, float* __restrict__ gvc) {
  const int h = blockIdx.x, dd = threadIdx.x;
  const short* vh = vThi + ((size_t)(h * 64 + dd)) * S;
  const short* vl = vTlo + ((size_t)(h * 64 + dd)) * S;
  float run = 0.f;
#pragma unroll 8
  for (int k = 0; k < S; ++k) {
    run += g[h * S + k] * (bf2f(vh[k]) + bf2f(vl[k]));
    gvc[((size_t)(h * S + k)) * 64 + dd] = run;
  }
}

// 64x64x48 f32 score tile: s[r][c] += sum_j Q[j][ty*4+r] * Kt[j][tx*4+c]
__device__ __forceinline__ void score_gemm(
    const float (*__restrict__ Q)[64], const float (*__restrict__ Kt)[64],
    int ty, int tx, float s[4][4]) {
#pragma unroll 8
  for (int j = 0; j < QKD; ++j) {
    float4 a4 = *(const float4*)&Q[j][ty * 4];
    float4 b4 = *(const float4*)&Kt[j][tx * 4];
    const float a[4] = {a4.x, a4.y, a4.z, a4.w};
    const float b[4] = {b4.x, b4.y, b4.z, b4.w};
#pragma unroll
    for (int r = 0; r < 4; ++r)
#pragma unroll
      for (int c = 0; c < 4; ++c) s[r][c] += a[r] * b[c];
  }
}

// --------- Pass D: f32 scores (exact signs) + split-bf16 MFMA PV + epilogue
__global__ __launch_bounds__(256) void attn_out(
    const float* __restrict__ qfT, const float* __restrict__ kfT,
    const short* __restrict__ vThi, const short* __restrict__ vTlo,
    const float* __restrict__ mIn, const float* __restrict__ rdIn,
    const float* __restrict__ gvc, const float* __restrict__ lamPtr,
    const float* __restrict__ normW, float* __restrict__ normed) {
  const int tile = tile_order(blockIdx.x), h = blockIdx.y;
  const int q0 = tile * 64;
  const int h2a = 2 * h, h2b = 2 * h + 1;
  __shared__ float Q1[QKD][64], Q2[QKD][64], Ks[QKD][64];
  __shared__ __align__(16) short ph_s[64 * 72], pl_s[64 * 72];
  __shared__ float m1s[64], r1s[64], m2s[64], r2s[64];
  __shared__ float ssb[64][2];
  __shared__ float rs[64];
  const int tid = threadIdx.x, ty = tid >> 4, tx = tid & 15;
  const int lane = tid & 63, w = tid >> 6;
  const int qsub = w >> 1, sub2 = w & 1;
  const float lam = *lamPtr;
  const short* vbh = vThi + ((size_t)h * 64) * S;
  const short* vbl = vTlo + ((size_t)h * 64) * S;
  for (int idx = tid; idx < QKD * 64; idx += 256) {
    const int j = idx >> 6, qi = idx & 63;
    Q1[j][qi] = qfT[((size_t)(h2a * QKD + j)) * S + q0 + qi];
    Q2[j][qi] = qfT[((size_t)(h2b * QKD + j)) * S + q0 + qi];
  }
  if (tid < 64) {
    m1s[tid] = mIn[h2a * S + q0 + tid];
    r1s[tid] = rdIn[h2a * S + q0 + tid];
    m2s[tid] = mIn[h2b * S + q0 + tid];
    r2s[tid] = rdIn[h2b * S + q0 + tid];
  }
  f32x16 oacc = fzero16();
  for (int kt = 0; kt <= tile; ++kt) {
    const int k0 = kt * 64;
    __syncthreads();
    for (int idx = tid; idx < QKD * 64; idx += 256) {
      const int j = idx >> 6, ki = idx & 63;
      Ks[j][ki] = kfT[((size_t)(h2a * QKD + j)) * S + k0 + ki];
    }
    __syncthreads();
    float s1[4][4] = {};
    score_gemm(Q1, Ks, ty, tx, s1);
    __syncthreads();
    for (int idx = tid; idx < QKD * 64; idx += 256) {
      const int j = idx >> 6, ki = idx & 63;
      Ks[j][ki] = kfT[((size_t)(h2b * QKD + j)) * S + k0 + ki];
    }
    __syncthreads();
    float s2[4][4] = {};
    score_gemm(Q2, Ks, ty, tx, s2);
    const bool diag = (kt == tile);
#pragma unroll
    for (int r = 0; r < 4; ++r) {
      const int row = ty * 4 + r;
      const float mm1 = m1s[row], rr1 = r1s[row];
      const float mm2 = m2s[row], rr2 = r2s[row];
#pragma unroll
      for (int c = 0; c < 4; ++c) {
        const int col = tx * 4 + c;
        float p = 0.f;
        if (!diag || col <= row) {
          const float v1 = s1[r][c] * SCALE, v2 = s2[r][c] * SCALE;
          const float sg1 = (v1 > 0.f) ? 1.f : ((v1 < 0.f) ? -1.f : 0.f);
          const float sg2 = (v2 > 0.f) ? 1.f : ((v2 < 0.f) ? -1.f : 0.f);
          p = sg1 * __expf(fabsf(v1) - mm1) * rr1
            - lam * (sg2 * __expf(fabsf(v2) - mm2) * rr2);
        }
        const short ph = f2bf(p);
        ph_s[row * 72 + col] = ph;
        pl_s[row * 72 + col] = f2bf(p - bf2f(ph));
      }
    }
    __syncthreads();
    // PV quadrant via MFMA: split P x split V (Ph*Vh + Ph*Vl + Pl*Vh), K=64
#pragma unroll
    for (int t = 0; t < 4; ++t) {
      bf16x8 pa = frag72(ph_s, lane, qsub, t);
      bf16x8 pl = frag72(pl_s, lane, qsub, t);
      const size_t voff = ((size_t)((lane & 31) + 32 * sub2)) * S + k0 +
                          ((lane >> 5) << 3) + 16 * t;
      bf16x8 vh = *(const bf16x8*)(vbh + voff);
      bf16x8 vl = *(const bf16x8*)(vbl + voff);
      oacc = __builtin_amdgcn_mfma_f32_32x32x16_bf16(pa, vh, oacc, 0, 0, 0);
      oacc = __builtin_amdgcn_mfma_f32_32x32x16_bf16(pa, vl, oacc, 0, 0, 0);
      oacc = __builtin_amdgcn_mfma_f32_32x32x16_bf16(pl, vh, oacc, 0, 0, 0);
    }
  }
  // epilogue: + lam*gvc, fused rmsnorm over d=64, store
  const int dloc = 32 * sub2 + (lane & 31);
  float vals[16], sq[16];
#pragma unroll
  for (int r = 0; r < 16; ++r) {
    const int row = d_rowpat(r, lane) + 32 * qsub;
    vals[r] = oacc[r] + lam * gvc[((size_t)(h * S + q0 + row)) * 64 + dloc];
    sq[r] = vals[r] * vals[r];
  }
#pragma unroll
  for (int o = 1; o <= 16; o <<= 1)
#pragma unroll
    for (int r = 0; r < 16; ++r) sq[r] += __shfl_xor(sq[r], o);
  if ((lane & 31) == 0) {
#pragma unroll
    for (int r = 0; r < 16; ++r)
      ssb[d_rowpat(r, lane) + 32 * qsub][sub2] = sq[r];
  }
  __syncthreads();
  if (tid < 64) rs[tid] = rsqrtf((ssb[tid][0] + ssb[tid][1]) * (1.0f / 64.0f) + EPS);
  __syncthreads();
#pragma unroll
  for (int r = 0; r < 16; ++r) {
    const int row = d_rowpat(r, lane) + 32 * qsub;
    normed[(size_t)(q0 + row) * D + h * 64 + dloc] = vals[r] * rs[row] * normW[dloc];
  }
}

// ----------------------------------------------------------------- launch
extern "C" void kernel_launch(void* const* d_in, const int* in_sizes, int n_in,
                              void* d_out, int out_size, void* d_ws, size_t ws_size,
                              hipStream_t stream) {
  const float* x     = (const float*)d_in[0];
  const float* freqs = (const float*)d_in[2];
  const float* Wkvd  = (const float*)d_in[3];
  const float* Wqd   = (const float*)d_in[4];
  const float* kvnw  = (const float*)d_in[5];
  const float* qnw   = (const float*)d_in[6];
  const float* Wkvup = (const float*)d_in[7];
  const float* Wqup  = (const float*)d_in[8];
  const float* lk1   = (const float*)d_in[9];
  const float* lk2   = (const float*)d_in[10];
  const float* lq1   = (const float*)d_in[11];
  const float* lq2   = (const float*)d_in[12];
  const float* normw = (const float*)d_in[13];
  const float* Wo    = (const float*)d_in[14];
  float* out = (float*)d_out;

  float* ws = (float*)d_ws;
  float* c      = ws;                          // S*288
  float* ckv    = c     + (size_t)S * 288;     // S*256
  float* cqr    = ckv   + (size_t)S * 256;     // S*384
  float* cq     = cqr   + (size_t)S * 384;     // S*384
  float* kvbuf  = cq    + (size_t)S * 384;     // S*2048
  float* qp     = kvbuf + (size_t)S * 2048;    // S*1536
  float* qfT    = qp    + (size_t)S * 1536;    // 32*48*S f32
  float* kfT    = qfT   + (size_t)H2 * QKD * S;
  short* qhi    = (short*)(kfT + (size_t)H2 * QKD * S);  // each 32*S*48 bf16
  short* qlo    = qhi + (size_t)H2 * S * 48;
  short* khi    = qlo + (size_t)H2 * S * 48;
  short* klo    = khi + (size_t)H2 * S * 48;
  short* vThi   = klo + (size_t)H2 * S * 48;   // 16*64*S bf16
  short* vTlo   = vThi + (size_t)NH * 64 * S;
  float* mbuf   = (float*)(vTlo + (size_t)NH * 64 * S);  // 32*S
  float* rdbuf  = mbuf  + (size_t)H2 * S;      // 32*S
  float* gbuf   = rdbuf + (size_t)H2 * S;      // 16*S
  float* lam    = gbuf  + (size_t)NH * S;      // 1
  float* gvc    = kvbuf;                       // overlay (dead after assemble)
  float* normed = qp;                          // overlay (dead after assemble)

  // 1. down-projections
  gemm_f32<<<dim3(3, S / 128), 256, 0, stream>>>(x, Wkvd, c, S, D, 288);
  gemm_f32<<<dim3(3, S / 128), 256, 0, stream>>>(x, Wqd, cqr, S, D, 384);
  // 2. rmsnorms
  rmsnorm_rows<<<S, 256, 0, stream>>>(c, kvnw, ckv, 288, 256);
  rmsnorm_rows<<<S, 256, 0, stream>>>(cqr, qnw, cq, 384, 384);
  // 3. up-projections
  gemm_f32<<<dim3(16, S / 128), 256, 0, stream>>>(ckv, Wkvup, kvbuf, S, 256, 2048);
  gemm_f32<<<dim3(12, S / 128), 256, 0, stream>>>(cq, Wqup, qp, S, 384, 1536);
  // 4. assemble heads (RoPE), f32 + hi/lo bf16 views, V^T hi/lo, lam
  assemble_qk<<<dim3(H2, S / 64), 64, 0, stream>>>(qp, kvbuf, c, freqs,
                                                   qfT, kfT, qhi, qlo, khi, klo);
  assemble_v<<<dim3(NH, S / 64), 256, 0, stream>>>(kvbuf, vThi, vTlo);
  compute_lam<<<1, 64, 0, stream>>>(lk1, lk2, lq1, lq2, lam);
  // 5. attention passes
  attn_md<<<dim3(32, H2), 256, 0, stream>>>(qhi, qlo, khi, klo, mbuf, rdbuf);
  attn_g<<<dim3(32, NH), 256, 0, stream>>>(qhi, qlo, khi, klo, mbuf, rdbuf, gbuf);
  attn_gvc<<<NH, 64, 0, stream>>>(gbuf, vThi, vTlo, gvc);
  attn_out<<<dim3(32, NH), 256, 0, stream>>>(qfT, kfT, vThi, vTlo, mbuf, rdbuf,
                                             gvc, lam, normw, normed);
  // 6. output projection
  gemm_f32<<<dim3(8, S / 128), 256, 0, stream>>>(normed, Wo, out, S, D, D);
}